// Round 8
// baseline (578.854 us; speedup 1.0000x reference)
//
#include <hip/hip_runtime.h>
#include <hip/hip_cooperative_groups.h>

namespace cg = cooperative_groups;

#define S_LEN 32768
#define D_DIM 1024
#define L_LAB 64
#define LC 32                     // owned steps per chunk (fwd + backtrack unit)
#define NCH (S_LEN / LC)          // 1024 chunks = 1024 blocks x 64 thr (4/CU, co-resident)
#define H_WARM 12                 // warm-up steps
#define NSUP 32                   // supers
#define SUPC 32                   // chunks per super (NSUP*SUPC == NCH)

// workspace layout (bytes)
#define EM_OFF   0                                  // float em[S][64]   = 8 MB
#define BP_OFF   (S_LEN * 64 * 4)                   // uchar bp[S][64]   = 2 MB
#define MAPS_OFF (BP_OFF + S_LEN * 64)              // uchar maps[NCH][64] = 64 KB
#define AUX_OFF  (MAPS_OFF + NCH * 64)              // psum/best/bt + sbl[32] + sm[32][64]
#define WIN_OFF  (AUX_OFF + 4096)                   // float win[NCH]
#define END_OFF  (WIN_OFF + NCH * 4)                // float endsc[NCH]
#define FIN_OFF  (END_OFF + NCH * 4)                // float finrow[64]
#define WBF_OFF  (FIN_OFF + 256)                    // ushort Wbf[64][1024] = 128 KB

typedef __attribute__((ext_vector_type(8))) short short8;
typedef __attribute__((ext_vector_type(4))) float floatx4;

__device__ inline unsigned short f32_bf16_rne(float f) {
    unsigned v = __float_as_uint(f);
    v += 0x7FFFu + ((v >> 16) & 1u);
    return (unsigned short)(v >> 16);
}
__device__ inline unsigned umax(unsigned a, unsigned b) { return a > b ? a : b; }

// ---------------------------------------------------------------------------
// Phase 0: W -> bf16 (RNE), once.
// ---------------------------------------------------------------------------
__global__ __launch_bounds__(256) void wconv_kernel(
        const float* __restrict__ W, unsigned short* __restrict__ Wbf) {
    int i = blockIdx.x * 256 + threadIdx.x;
    Wbf[i] = f32_bf16_rne(W[i]);
}

// ---------------------------------------------------------------------------
// Phase 1: emissions = bf16(feats) @ bf16(W).T + b (LDS-staged, unchanged).
// ---------------------------------------------------------------------------
__global__ __launch_bounds__(256) __attribute__((amdgpu_waves_per_eu(2, 2)))
void emis_kernel(
        const float* __restrict__ feats, const unsigned short* __restrict__ Wbf,
        const float* __restrict__ bvec, float* __restrict__ em) {
    __shared__ __align__(16) unsigned short As[64 * 72];
    __shared__ __align__(16) unsigned short Bs[64 * 72];

    const int tid = threadIdx.x;
    const int lan = tid & 15;
    const int q   = (tid >> 4) & 3;
    const int w   = tid >> 6;
    const int row0 = blockIdx.x * 64;

    floatx4 acc[4];
#pragma unroll
    for (int nt = 0; nt < 4; ++nt) acc[nt] = (floatx4){0.f, 0.f, 0.f, 0.f};

    for (int kb = 0; kb < D_DIM; kb += 64) {
        __syncthreads();
#pragma unroll
        for (int i = 0; i < 4; ++i) {
            int gi = tid + i * 256;            // 1024 granules of 4 elements
            int m = gi >> 4, g = gi & 15;
            float4 v = *(const float4*)&feats[(size_t)(row0 + m) * D_DIM + kb + g * 4];
            unsigned h0 = f32_bf16_rne(v.x) | ((unsigned)f32_bf16_rne(v.y) << 16);
            unsigned h1 = f32_bf16_rne(v.z) | ((unsigned)f32_bf16_rne(v.w) << 16);
            *(uint2*)&As[m * 72 + g * 4] = (uint2){h0, h1};
        }
#pragma unroll
        for (int i = 0; i < 2; ++i) {
            int gi = tid + i * 256;
            int m = gi >> 3, g = gi & 7;
            *(uint4*)&Bs[m * 72 + g * 8] =
                *(const uint4*)&Wbf[(size_t)m * D_DIM + kb + g * 8];
        }
        __syncthreads();

#pragma unroll
        for (int cc = 0; cc < 2; ++cc) {
            int koff = cc * 32 + q * 8;
            int m_loc = w * 16 + lan;
            short8 av = *(const short8*)&As[m_loc * 72 + koff];
#pragma unroll
            for (int nt = 0; nt < 4; ++nt) {
                int label = nt * 16 + lan;
                short8 bv = *(const short8*)&Bs[label * 72 + koff];
                acc[nt] = __builtin_amdgcn_mfma_f32_16x16x32_bf16(av, bv, acc[nt], 0, 0, 0);
            }
        }
    }

    // epilogue: C/D layout col=lane&15, row=(lane>>4)*4+reg
#pragma unroll
    for (int nt = 0; nt < 4; ++nt) {
        int label = nt * 16 + lan;
        float bias = bvec[label];
#pragma unroll
        for (int r = 0; r < 4; ++r) {
            int row = row0 + w * 16 + q * 4 + r;
            em[(size_t)row * 64 + label] = acc[nt][r] + bias;
        }
    }
}

// ---------------------------------------------------------------------------
// Phase 2-4 merged (R7): ONE cooperative kernel = fwd + finish + backtrack.
// grid = NCH blocks x 64 thr = 4 blocks/CU at waves_per_eu(1,1) -> co-resident
// by construction; 3 grid.sync()s replace 2 kernel launches. Numerics are
// bit-identical to R6 (exact shifted key, proven absmax 60).
// ---------------------------------------------------------------------------
__global__ __launch_bounds__(64) __attribute__((amdgpu_waves_per_eu(1, 1)))
void viterbi_coop(
        const float* __restrict__ em, const float* __restrict__ T,
        unsigned char* __restrict__ bp, unsigned char* __restrict__ maps,
        float* __restrict__ win, float* __restrict__ endsc,
        float* __restrict__ finrow, char* __restrict__ aux,
        float* __restrict__ out) {
    cg::grid_group grid = cg::this_grid();
    const int j = threadIdx.x;
    const int c = blockIdx.x;
    const int a = c * LC;
    const int bend = a + LC;

    float* psumg = (float*)aux;               // telescoped score correction
    float* bestg = (float*)(aux + 4);         // best final score (local frame)
    int*   btg   = (int*)(aux + 8);           // argmax final tag
    unsigned char* sbl = (unsigned char*)(aux + 16);   // [NSUP] super-boundary tags
    unsigned char* smg = (unsigned char*)(aux + 64);   // [NSUP][64] supermaps

    // ======================= PHASE A: forward =======================
    {
        float Trow[64];
#pragma unroll
        for (int i = 0; i < 16; ++i)
            ((float4*)Trow)[i] = ((const float4*)(T + j * 64))[i];
#pragma unroll
        for (int i = 0; i < 64; ++i) Trow[i] += 32768.0f;

        int t0 = a - 1 - H_WARM;
        if (t0 < 0) t0 = 0;

        float sc;
        if (t0 == 0) {
            sc = Trow[0] + (em[j] - 32768.0f);
        } else {
            sc = em[(size_t)t0 * 64 + j];
        }

        // value-only step (warm-up); 4 accumulators, 8-deep max3 chains.
        auto step = [&](float e) {
            int sci = __float_as_int(sc);
            float v0 = 0.f, v1 = 0.f, v2 = 0.f, v3 = 0.f;  // candidates > 12000
#pragma unroll
            for (int k = 0; k < 8; ++k) {
                float a0 = __int_as_float(__builtin_amdgcn_readlane(sci, k)) + Trow[k];
                float a1 = __int_as_float(__builtin_amdgcn_readlane(sci, k + 16)) + Trow[k + 16];
                float a2 = __int_as_float(__builtin_amdgcn_readlane(sci, k + 32)) + Trow[k + 32];
                float a3 = __int_as_float(__builtin_amdgcn_readlane(sci, k + 48)) + Trow[k + 48];
                v0 = fmaxf(fmaxf(v0, a0), a1);   // v_max3_f32
                v1 = fmaxf(fmaxf(v1, a2), a3);
            }
#pragma unroll
            for (int k = 8; k < 16; ++k) {
                float a0 = __int_as_float(__builtin_amdgcn_readlane(sci, k)) + Trow[k];
                float a1 = __int_as_float(__builtin_amdgcn_readlane(sci, k + 16)) + Trow[k + 16];
                float a2 = __int_as_float(__builtin_amdgcn_readlane(sci, k + 32)) + Trow[k + 32];
                float a3 = __int_as_float(__builtin_amdgcn_readlane(sci, k + 48)) + Trow[k + 48];
                v2 = fmaxf(fmaxf(v2, a0), a1);
                v3 = fmaxf(fmaxf(v3, a2), a3);
            }
            sc = e + fmaxf(fmaxf(v0, v1), fmaxf(v2, v3));
        };

        int bi = 0;
        // key-only step (owned): exact value + argmax from the shifted key.
        auto stepx = [&](float e) {
            int sci = __float_as_int(sc);
            unsigned m0 = 0u, m1 = 0u, m2 = 0u, m3 = 0u;
#pragma unroll
            for (int k = 0; k < 8; ++k) {
                float a0 = __int_as_float(__builtin_amdgcn_readlane(sci, k)) + Trow[k];
                float a1 = __int_as_float(__builtin_amdgcn_readlane(sci, k + 16)) + Trow[k + 16];
                float a2 = __int_as_float(__builtin_amdgcn_readlane(sci, k + 32)) + Trow[k + 32];
                float a3 = __int_as_float(__builtin_amdgcn_readlane(sci, k + 48)) + Trow[k + 48];
                unsigned k0 = ((unsigned)__float_as_int(a0) << 6) | (unsigned)(63 - k);
                unsigned k1 = ((unsigned)__float_as_int(a1) << 6) | (unsigned)(63 - (k + 16));
                unsigned k2 = ((unsigned)__float_as_int(a2) << 6) | (unsigned)(63 - (k + 32));
                unsigned k3 = ((unsigned)__float_as_int(a3) << 6) | (unsigned)(63 - (k + 48));
                m0 = umax(umax(m0, k0), k1);     // v_max3_u32
                m1 = umax(umax(m1, k2), k3);
            }
#pragma unroll
            for (int k = 8; k < 16; ++k) {
                float a0 = __int_as_float(__builtin_amdgcn_readlane(sci, k)) + Trow[k];
                float a1 = __int_as_float(__builtin_amdgcn_readlane(sci, k + 16)) + Trow[k + 16];
                float a2 = __int_as_float(__builtin_amdgcn_readlane(sci, k + 32)) + Trow[k + 32];
                float a3 = __int_as_float(__builtin_amdgcn_readlane(sci, k + 48)) + Trow[k + 48];
                unsigned k0 = ((unsigned)__float_as_int(a0) << 6) | (unsigned)(63 - k);
                unsigned k1 = ((unsigned)__float_as_int(a1) << 6) | (unsigned)(63 - (k + 16));
                unsigned k2 = ((unsigned)__float_as_int(a2) << 6) | (unsigned)(63 - (k + 32));
                unsigned k3 = ((unsigned)__float_as_int(a3) << 6) | (unsigned)(63 - (k + 48));
                m2 = umax(umax(m2, k0), k1);
                m3 = umax(umax(m3, k2), k3);
            }
            unsigned mm = umax(umax(m0, m1), umax(m2, m3));
            bi = (int)(mm & 63u) ^ 63;
            sc = e + __uint_as_float((mm >> 6) | 0x44000000u);   // exact
        };

        // ---- warm-up: t in [t0+1, a), no stores ----
        int t = t0 + 1;
        if (t < a) {
            float p0 = em[(size_t)(t + 0) * 64 + j] - 32768.0f;
            float p1 = em[(size_t)(t + 1) * 64 + j] - 32768.0f;
            float p2 = em[(size_t)(t + 2) * 64 + j] - 32768.0f;
            float p3 = em[(size_t)(t + 3) * 64 + j] - 32768.0f;
            for (; t + 3 < a; t += 4) {
                float n0 = em[(size_t)(t + 4) * 64 + j] - 32768.0f;
                float n1 = em[(size_t)(t + 5) * 64 + j] - 32768.0f;
                float n2 = em[(size_t)(t + 6) * 64 + j] - 32768.0f;
                float n3 = em[(size_t)(t + 7) * 64 + j] - 32768.0f;
                step(p0); step(p1); step(p2); step(p3);
                p0 = n0; p1 = n1; p2 = n2; p3 = n3;
            }
            for (; t < a; ++t) { step(p0); p0 = p1; p1 = p2; p2 = p3; }
        }
        if (c > 0 && j == 0) win[c] = sc;   // state-0 score entering owned

        // ---- owned: argmax + bp store + bpermute map composition ----
        int fmap = j;
        t = (a > 0) ? a : 1;
        {
            float p0 = em[(size_t)(t + 0) * 64 + j] - 32768.0f;
            float p1 = em[(size_t)(t + 1) * 64 + j] - 32768.0f;
            float p2 = em[(size_t)(t + 2) * 64 + j] - 32768.0f;
            float p3 = em[(size_t)(t + 3) * 64 + j] - 32768.0f;
            for (; t + 3 < bend; t += 4) {
                int t4 = t + 4 > S_LEN - 1 ? S_LEN - 1 : t + 4;
                int t5 = t + 5 > S_LEN - 1 ? S_LEN - 1 : t + 5;
                int t6 = t + 6 > S_LEN - 1 ? S_LEN - 1 : t + 6;
                int t7 = t + 7 > S_LEN - 1 ? S_LEN - 1 : t + 7;
                float n0 = em[(size_t)t4 * 64 + j] - 32768.0f;
                float n1 = em[(size_t)t5 * 64 + j] - 32768.0f;
                float n2 = em[(size_t)t6 * 64 + j] - 32768.0f;
                float n3 = em[(size_t)t7 * 64 + j] - 32768.0f;
                stepx(p0); bp[(size_t)(t + 0) * 64 + j] = (unsigned char)bi;
                fmap = __builtin_amdgcn_ds_bpermute(bi << 2, fmap);
                stepx(p1); bp[(size_t)(t + 1) * 64 + j] = (unsigned char)bi;
                fmap = __builtin_amdgcn_ds_bpermute(bi << 2, fmap);
                stepx(p2); bp[(size_t)(t + 2) * 64 + j] = (unsigned char)bi;
                fmap = __builtin_amdgcn_ds_bpermute(bi << 2, fmap);
                stepx(p3); bp[(size_t)(t + 3) * 64 + j] = (unsigned char)bi;
                fmap = __builtin_amdgcn_ds_bpermute(bi << 2, fmap);
                p0 = n0; p1 = n1; p2 = n2; p3 = n3;
            }
            for (; t < bend; ++t) {
                stepx(p0); bp[(size_t)t * 64 + j] = (unsigned char)bi;
                fmap = __builtin_amdgcn_ds_bpermute(bi << 2, fmap);
                p0 = p1; p1 = p2; p2 = p3;
            }
        }

        maps[c * 64 + j] = (unsigned char)fmap;
        if (j == 0) endsc[c] = sc;
        if (c == NCH - 1) finrow[j] = sc;
    }
    grid.sync();

    // ======================= PHASE B: finish prep (parallel) =======
    if (c < NSUP) {
        // supermap s=c : compose its 32 chunk maps via bpermute chain
        int x = j;
#pragma unroll 4
        for (int q = SUPC - 1; q >= 0; --q) {
            int mq = maps[(c * SUPC + q) * 64 + j];
            x = __builtin_amdgcn_ds_bpermute(x << 2, mq);
        }
        smg[c * 64 + j] = (unsigned char)x;
    } else if (c == NSUP) {
        // telescoped score correction
        float p = 0.f;
#pragma unroll
        for (int i = 0; i < NCH / 64; ++i) {
            int cc = 1 + j + i * 64;
            if (cc < NCH) p += endsc[cc - 1] - win[cc];
        }
#pragma unroll
        for (int off = 32; off; off >>= 1) p += __shfl_xor(p, off, 64);
        if (j == 0) *psumg = p;
    } else if (c == NSUP + 1) {
        // final-row argmax (+ END_TAG transition row)
        float f = finrow[j] + T[63 * 64 + j];
        float best = 0.f; int bt_ = 0;
#pragma unroll
        for (int k = 0; k < 64; ++k) {
            float fv = __int_as_float(__builtin_amdgcn_readlane(__float_as_int(f), k));
            if (k == 0) best = fv;
            else if (fv > best) { best = fv; bt_ = k; }
        }
        if (j == 0) { *bestg = best; *btg = bt_; }
    }
    grid.sync();

    // ======================= PHASE C: super stitch (block 0) =======
    if (c == 0) {
        int rows[NSUP];
#pragma unroll
        for (int s = 0; s < NSUP; ++s) rows[s] = smg[s * 64 + j];
        int x = __builtin_amdgcn_readfirstlane(*btg);
        if (j == 0) out[0] = *bestg + *psumg;
        int sbv = 0;
        if (j == NSUP - 1) sbv = x;
#pragma unroll
        for (int s = NSUP - 1; s >= 1; --s) {
            x = __builtin_amdgcn_readlane(rows[s], x);
            if (j == s - 1) sbv = x;
        }
        if (j < NSUP) sbl[j] = (unsigned char)sbv;
    }
    grid.sync();

    // ======================= PHASE D: per-chunk boundary + fill ====
    {
        const int s = c >> 5, q0 = c & 31;   // uniform per block
        // derive this chunk's end-boundary tag from the super boundary
        int rowsA[SUPC];
#pragma unroll
        for (int q = 1; q < SUPC; ++q)
            rowsA[q] = (q > q0) ? (int)maps[(s * SUPC + q) * 64 + j] : 0;
        int x = __builtin_amdgcn_readfirstlane((int)sbl[s]);
#pragma unroll
        for (int q = SUPC - 1; q >= 1; --q)
            if (q > q0) x = __builtin_amdgcn_readlane(rowsA[q], x);

        // backtrack the chunk via readlane chain
        int rowsB[LC];
#pragma unroll
        for (int tt = 1; tt < LC; ++tt)
            rowsB[tt] = bp[((size_t)c * LC + tt) * 64 + j];
        int tv = 0;
        if (j == LC - 1) tv = x;
#pragma unroll
        for (int tt = LC - 1; tt >= 1; --tt) {
            x = __builtin_amdgcn_readlane(rowsB[tt], x);
            if (j == tt - 1) tv = x;
        }
        if (j < LC) out[1 + c * LC + j] = (float)tv;
    }
}

extern "C" void kernel_launch(void* const* d_in, const int* in_sizes, int n_in,
                              void* d_out, int out_size, void* d_ws, size_t ws_size,
                              hipStream_t stream) {
    const float* feats = (const float*)d_in[0];   // [S, D]
    const float* W     = (const float*)d_in[1];   // [L, D]
    const float* b     = (const float*)d_in[2];   // [L]
    const float* T     = (const float*)d_in[3];   // [L, L]
    float* out = (float*)d_out;                   // [0]=score, [1..S]=tags

    char* ws = (char*)d_ws;
    float*          em     = (float*)(ws + EM_OFF);
    unsigned char*  bp     = (unsigned char*)(ws + BP_OFF);
    unsigned char*  maps   = (unsigned char*)(ws + MAPS_OFF);
    char*           aux    = ws + AUX_OFF;
    float*          win    = (float*)(ws + WIN_OFF);
    float*          endsc  = (float*)(ws + END_OFF);
    float*          finrow = (float*)(ws + FIN_OFF);
    unsigned short* Wbf    = (unsigned short*)(ws + WBF_OFF);

    wconv_kernel<<<(L_LAB * D_DIM) / 256, 256, 0, stream>>>(W, Wbf);
    emis_kernel<<<S_LEN / 64, 256, 0, stream>>>(feats, Wbf, b, em);

    void* kargs[] = {(void*)&em, (void*)&T, (void*)&bp, (void*)&maps,
                     (void*)&win, (void*)&endsc, (void*)&finrow,
                     (void*)&aux, (void*)&out};
    hipLaunchCooperativeKernel(reinterpret_cast<void*>(&viterbi_coop),
                               dim3(NCH), dim3(64), kargs, 0, stream);
}

// Round 10
// 251.454 us; speedup vs baseline: 2.3020x; 2.3020x over previous
//
#include <hip/hip_runtime.h>

#define S_LEN 32768
#define D_DIM 1024
#define L_LAB 64
#define LC 32                     // owned steps per chunk (fwd + backtrack unit)
#define NCH (S_LEN / LC)          // 1024 chunks = 1024 waves (fills all SIMDs)
#define H_WARM 12                 // warm-up steps
#define NSUP 32                   // supers in finish
#define SUPC 32                   // chunks per super (NSUP*SUPC == NCH)

// workspace layout (bytes)
#define EM_OFF   0                                  // float em[S][64]   = 8 MB
#define BP_OFF   (S_LEN * 64 * 4)                   // uchar bp[S][64]   = 2 MB
#define MAPS_OFF (BP_OFF + S_LEN * 64)              // uchar maps[NCH][64] = 64 KB
#define BND_OFF  (MAPS_OFF + NCH * 64)              // uchar bnd[NCH]
#define WIN_OFF  (BND_OFF + 1024)                   // float win[NCH]
#define END_OFF  (WIN_OFF + NCH * 4)                // float endsc[NCH]
#define FIN_OFF  (END_OFF + NCH * 4)                // float finrow[64]
#define WBF_OFF  (FIN_OFF + 256)                    // ushort Wbf[64][1024] = 128 KB

typedef __attribute__((ext_vector_type(8))) short short8;
typedef __attribute__((ext_vector_type(4))) float floatx4;

__device__ inline unsigned short f32_bf16_rne(float f) {
    unsigned v = __float_as_uint(f);
    v += 0x7FFFu + ((v >> 16) & 1u);
    return (unsigned short)(v >> 16);
}
__device__ inline unsigned umax(unsigned a, unsigned b) { return a > b ? a : b; }

// ---------------------------------------------------------------------------
// Phase 0: W -> bf16 (RNE), once.
// ---------------------------------------------------------------------------
__global__ __launch_bounds__(256) void wconv_kernel(
        const float* __restrict__ W, unsigned short* __restrict__ Wbf) {
    int i = blockIdx.x * 256 + threadIdx.x;
    Wbf[i] = f32_bf16_rne(W[i]);
}

// ---------------------------------------------------------------------------
// Phase 1 (R8): emissions = bf16(feats) @ bf16(W).T + b.
// 32-row tiles -> 1024 blocks = 4 blocks/CU (was 2): doubles resident waves
// so barrier-drain + HBM latency of one block hides under others (m114
// wave-level overlap). Per wave: row-tile rt = w>>1, label-pair lb = (w&1)*2,
// 2 acc tiles. em output bit-identical to R6 (same RNE, same MFMA order).
// ---------------------------------------------------------------------------
__global__ __launch_bounds__(256) __attribute__((amdgpu_waves_per_eu(4, 4)))
void emis_kernel(
        const float* __restrict__ feats, const unsigned short* __restrict__ Wbf,
        const float* __restrict__ bvec, float* __restrict__ em) {
    __shared__ __align__(16) unsigned short As[32 * 72];   // bf16 feats tile
    __shared__ __align__(16) unsigned short Bs[64 * 72];   // bf16 W tile

    const int tid = threadIdx.x;
    const int lan = tid & 15;
    const int q   = (tid >> 4) & 3;
    const int w   = tid >> 6;
    const int rt  = w >> 1;           // row-tile (0/1)
    const int lb  = (w & 1) * 2;      // label-tile base (0/2)
    const int row0 = blockIdx.x * 32;

    floatx4 acc[2];
#pragma unroll
    for (int nt = 0; nt < 2; ++nt) acc[nt] = (floatx4){0.f, 0.f, 0.f, 0.f};

    for (int kb = 0; kb < D_DIM; kb += 64) {
        __syncthreads();
        // stage A: 32 rows x 64 k; 512 granules of 4 el, 2/thread
#pragma unroll
        for (int i = 0; i < 2; ++i) {
            int gi = tid + i * 256;
            int m = gi >> 4, g = gi & 15;
            float4 v = *(const float4*)&feats[(size_t)(row0 + m) * D_DIM + kb + g * 4];
            unsigned h0 = f32_bf16_rne(v.x) | ((unsigned)f32_bf16_rne(v.y) << 16);
            unsigned h1 = f32_bf16_rne(v.z) | ((unsigned)f32_bf16_rne(v.w) << 16);
            *(uint2*)&As[m * 72 + g * 4] = (uint2){h0, h1};
        }
        // stage B: 64 labels x 64 k bf16, straight copy (512 uint4, 2/thread)
#pragma unroll
        for (int i = 0; i < 2; ++i) {
            int gi = tid + i * 256;
            int m = gi >> 3, g = gi & 7;
            *(uint4*)&Bs[m * 72 + g * 8] =
                *(const uint4*)&Wbf[(size_t)m * D_DIM + kb + g * 8];
        }
        __syncthreads();

#pragma unroll
        for (int cc = 0; cc < 2; ++cc) {
            int koff = cc * 32 + q * 8;
            short8 av = *(const short8*)&As[(rt * 16 + lan) * 72 + koff];
#pragma unroll
            for (int nt = 0; nt < 2; ++nt) {
                short8 bv = *(const short8*)&Bs[((lb + nt) * 16 + lan) * 72 + koff];
                acc[nt] = __builtin_amdgcn_mfma_f32_16x16x32_bf16(av, bv, acc[nt], 0, 0, 0);
            }
        }
    }

    // epilogue: C/D layout col=lane&15, row=(lane>>4)*4+reg
#pragma unroll
    for (int nt = 0; nt < 2; ++nt) {
        int label = (lb + nt) * 16 + lan;
        float bias = bvec[label];
#pragma unroll
        for (int r = 0; r < 4; ++r) {
            int row = row0 + rt * 16 + q * 4 + r;
            em[(size_t)row * 64 + label] = acc[nt][r] + bias;
        }
    }
}

// ---------------------------------------------------------------------------
// Phase 2: forward + inline argmax + inline map composition (R6, unchanged).
// EXACT shifted key (proven absmax 60): candidates v = sc_i + Trow_b[i] in
// [12.6k, 33k] subset [2^13, 2^17) => top 6 bits of asint(v) constant.
// key = (asint(v) << 6) | (63-i) compared unsigned; value reconstructed
// exactly via (key >> 6) | 0x44000000.
// ---------------------------------------------------------------------------
__global__ __launch_bounds__(64) __attribute__((amdgpu_waves_per_eu(1, 1)))
void fwd_chunks(
        const float* __restrict__ em, const float* __restrict__ T,
        unsigned char* __restrict__ bp, unsigned char* __restrict__ maps,
        float* __restrict__ win, float* __restrict__ endsc,
        float* __restrict__ finrow) {
    const int j = threadIdx.x;
    const int c = blockIdx.x;
    const int a = c * LC;
    const int bend = a + LC;

    float Trow[64];
#pragma unroll
    for (int i = 0; i < 16; ++i)
        ((float4*)Trow)[i] = ((const float4*)(T + j * 64))[i];
#pragma unroll
    for (int i = 0; i < 64; ++i) Trow[i] += 32768.0f;

    int t0 = a - 1 - H_WARM;
    if (t0 < 0) t0 = 0;

    float sc;
    if (t0 == 0) {
        sc = Trow[0] + (em[j] - 32768.0f);
    } else {
        sc = em[(size_t)t0 * 64 + j];
    }

    // value-only step (warm-up); 4 accumulators, 8-deep max3 chains.
    auto step = [&](float e) {
        int sci = __float_as_int(sc);
        float v0 = 0.f, v1 = 0.f, v2 = 0.f, v3 = 0.f;   // candidates all > 12000
#pragma unroll
        for (int k = 0; k < 8; ++k) {
            float a0 = __int_as_float(__builtin_amdgcn_readlane(sci, k)) + Trow[k];
            float a1 = __int_as_float(__builtin_amdgcn_readlane(sci, k + 16)) + Trow[k + 16];
            float a2 = __int_as_float(__builtin_amdgcn_readlane(sci, k + 32)) + Trow[k + 32];
            float a3 = __int_as_float(__builtin_amdgcn_readlane(sci, k + 48)) + Trow[k + 48];
            v0 = fmaxf(fmaxf(v0, a0), a1);   // v_max3_f32
            v1 = fmaxf(fmaxf(v1, a2), a3);
        }
#pragma unroll
        for (int k = 8; k < 16; ++k) {
            float a0 = __int_as_float(__builtin_amdgcn_readlane(sci, k)) + Trow[k];
            float a1 = __int_as_float(__builtin_amdgcn_readlane(sci, k + 16)) + Trow[k + 16];
            float a2 = __int_as_float(__builtin_amdgcn_readlane(sci, k + 32)) + Trow[k + 32];
            float a3 = __int_as_float(__builtin_amdgcn_readlane(sci, k + 48)) + Trow[k + 48];
            v2 = fmaxf(fmaxf(v2, a0), a1);
            v3 = fmaxf(fmaxf(v3, a2), a3);
        }
        sc = e + fmaxf(fmaxf(v0, v1), fmaxf(v2, v3));
    };

    int bi = 0;
    // key-only step (owned): exact value + argmax from the shifted key.
    auto stepx = [&](float e) {
        int sci = __float_as_int(sc);
        unsigned m0 = 0u, m1 = 0u, m2 = 0u, m3 = 0u;
#pragma unroll
        for (int k = 0; k < 8; ++k) {
            float a0 = __int_as_float(__builtin_amdgcn_readlane(sci, k)) + Trow[k];
            float a1 = __int_as_float(__builtin_amdgcn_readlane(sci, k + 16)) + Trow[k + 16];
            float a2 = __int_as_float(__builtin_amdgcn_readlane(sci, k + 32)) + Trow[k + 32];
            float a3 = __int_as_float(__builtin_amdgcn_readlane(sci, k + 48)) + Trow[k + 48];
            unsigned k0 = ((unsigned)__float_as_int(a0) << 6) | (unsigned)(63 - k);
            unsigned k1 = ((unsigned)__float_as_int(a1) << 6) | (unsigned)(63 - (k + 16));
            unsigned k2 = ((unsigned)__float_as_int(a2) << 6) | (unsigned)(63 - (k + 32));
            unsigned k3 = ((unsigned)__float_as_int(a3) << 6) | (unsigned)(63 - (k + 48));
            m0 = umax(umax(m0, k0), k1);     // v_max3_u32
            m1 = umax(umax(m1, k2), k3);
        }
#pragma unroll
        for (int k = 8; k < 16; ++k) {
            float a0 = __int_as_float(__builtin_amdgcn_readlane(sci, k)) + Trow[k];
            float a1 = __int_as_float(__builtin_amdgcn_readlane(sci, k + 16)) + Trow[k + 16];
            float a2 = __int_as_float(__builtin_amdgcn_readlane(sci, k + 32)) + Trow[k + 32];
            float a3 = __int_as_float(__builtin_amdgcn_readlane(sci, k + 48)) + Trow[k + 48];
            unsigned k0 = ((unsigned)__float_as_int(a0) << 6) | (unsigned)(63 - k);
            unsigned k1 = ((unsigned)__float_as_int(a1) << 6) | (unsigned)(63 - (k + 16));
            unsigned k2 = ((unsigned)__float_as_int(a2) << 6) | (unsigned)(63 - (k + 32));
            unsigned k3 = ((unsigned)__float_as_int(a3) << 6) | (unsigned)(63 - (k + 48));
            m2 = umax(umax(m2, k0), k1);
            m3 = umax(umax(m3, k2), k3);
        }
        unsigned mm = umax(umax(m0, m1), umax(m2, m3));
        bi = (int)(mm & 63u) ^ 63;
        sc = e + __uint_as_float((mm >> 6) | 0x44000000u);   // exact
    };

    // ---- warm-up: t in [t0+1, a), no stores ----
    int t = t0 + 1;
    if (t < a) {
        float p0 = em[(size_t)(t + 0) * 64 + j] - 32768.0f;
        float p1 = em[(size_t)(t + 1) * 64 + j] - 32768.0f;
        float p2 = em[(size_t)(t + 2) * 64 + j] - 32768.0f;
        float p3 = em[(size_t)(t + 3) * 64 + j] - 32768.0f;
        for (; t + 3 < a; t += 4) {
            float n0 = em[(size_t)(t + 4) * 64 + j] - 32768.0f;
            float n1 = em[(size_t)(t + 5) * 64 + j] - 32768.0f;
            float n2 = em[(size_t)(t + 6) * 64 + j] - 32768.0f;
            float n3 = em[(size_t)(t + 7) * 64 + j] - 32768.0f;
            step(p0); step(p1); step(p2); step(p3);
            p0 = n0; p1 = n1; p2 = n2; p3 = n3;
        }
        for (; t < a; ++t) { step(p0); p0 = p1; p1 = p2; p2 = p3; }
    }
    if (c > 0 && j == 0) win[c] = sc;   // state-0 score entering owned (t = a-1)

    // ---- owned: argmax + bp store + bpermute map composition ----
    int fmap = j;                        // identity; composes to end->(a-1)
    t = (a > 0) ? a : 1;
    {
        float p0 = em[(size_t)(t + 0) * 64 + j] - 32768.0f;
        float p1 = em[(size_t)(t + 1) * 64 + j] - 32768.0f;
        float p2 = em[(size_t)(t + 2) * 64 + j] - 32768.0f;
        float p3 = em[(size_t)(t + 3) * 64 + j] - 32768.0f;
        for (; t + 3 < bend; t += 4) {
            int t4 = t + 4 > S_LEN - 1 ? S_LEN - 1 : t + 4;
            int t5 = t + 5 > S_LEN - 1 ? S_LEN - 1 : t + 5;
            int t6 = t + 6 > S_LEN - 1 ? S_LEN - 1 : t + 6;
            int t7 = t + 7 > S_LEN - 1 ? S_LEN - 1 : t + 7;
            float n0 = em[(size_t)t4 * 64 + j] - 32768.0f;
            float n1 = em[(size_t)t5 * 64 + j] - 32768.0f;
            float n2 = em[(size_t)t6 * 64 + j] - 32768.0f;
            float n3 = em[(size_t)t7 * 64 + j] - 32768.0f;
            stepx(p0); bp[(size_t)(t + 0) * 64 + j] = (unsigned char)bi;
            fmap = __builtin_amdgcn_ds_bpermute(bi << 2, fmap);
            stepx(p1); bp[(size_t)(t + 1) * 64 + j] = (unsigned char)bi;
            fmap = __builtin_amdgcn_ds_bpermute(bi << 2, fmap);
            stepx(p2); bp[(size_t)(t + 2) * 64 + j] = (unsigned char)bi;
            fmap = __builtin_amdgcn_ds_bpermute(bi << 2, fmap);
            stepx(p3); bp[(size_t)(t + 3) * 64 + j] = (unsigned char)bi;
            fmap = __builtin_amdgcn_ds_bpermute(bi << 2, fmap);
            p0 = n0; p1 = n1; p2 = n2; p3 = n3;
        }
        for (; t < bend; ++t) {
            stepx(p0); bp[(size_t)t * 64 + j] = (unsigned char)bi;
            fmap = __builtin_amdgcn_ds_bpermute(bi << 2, fmap);
            p0 = p1; p1 = p2; p2 = p3;
        }
    }

    maps[c * 64 + j] = (unsigned char)fmap;     // end-of-chunk -> t=a-1
    if (j == 0) endsc[c] = sc;                  // state-0 score at t=bend-1
    if (c == NCH - 1) finrow[j] = sc;           // full final row
}

// ---------------------------------------------------------------------------
// Phase 3: telescoped score + argmax + hierarchical map stitching (R6).
// ---------------------------------------------------------------------------
__global__ __launch_bounds__(1024) void finish_kernel(
        const float* __restrict__ T, const float* __restrict__ win,
        const float* __restrict__ endsc, const float* __restrict__ finrow,
        const unsigned char* __restrict__ maps, float* __restrict__ out,
        unsigned char* __restrict__ bnd) {
    __shared__ unsigned char sm[NSUP * 64];
    __shared__ unsigned char sbl[NSUP];
    __shared__ float psum[16];
    const int tid = threadIdx.x;
    const int lane = tid & 63;
    const int wid = tid >> 6;

    // P0: telescoping partial sums (c = tid in [1, NCH))
    float p = 0.f;
    if (tid >= 1 && tid < NCH) p = endsc[tid - 1] - win[tid];
#pragma unroll
    for (int off = 32; off; off >>= 1) p += __shfl_xor(p, off, 64);
    if (lane == 0) psum[wid] = p;

    // P1: supermaps — wave w composes supers 2w, 2w+1 (32 bpermutes each)
#pragma unroll
    for (int r = 0; r < 2; ++r) {
        int s = wid * 2 + r;
        int x = lane;
#pragma unroll 4
        for (int q = SUPC - 1; q >= 0; --q) {
            int mq = maps[(s * SUPC + q) * 64 + lane];
            x = __builtin_amdgcn_ds_bpermute(x << 2, mq);
        }
        sm[s * 64 + lane] = (unsigned char)x;
    }
    __syncthreads();

    // P2: wave 0 — part total, final argmax, serial super chain (readlane)
    if (tid < 64) {
        float part = 0.f;
#pragma unroll
        for (int i = 0; i < 16; ++i) part += psum[i];

        float f = finrow[lane] + T[63 * 64 + lane];
        float best = 0.f; int bt_ = 0;
#pragma unroll
        for (int k = 0; k < 64; ++k) {
            float fv = __int_as_float(__builtin_amdgcn_readlane(__float_as_int(f), k));
            if (k == 0) best = fv;
            else if (fv > best) { best = fv; bt_ = k; }
        }
        if (lane == 0) out[0] = best + part;

        int rows[NSUP];
#pragma unroll
        for (int s = 0; s < NSUP; ++s) rows[s] = sm[s * 64 + lane];
        int x = bt_;                      // uniform across wave 0
        int sbv = 0;
        if (lane == NSUP - 1) sbv = x;
#pragma unroll
        for (int s = NSUP - 1; s >= 1; --s) {
            x = __builtin_amdgcn_readlane(rows[s], x);
            if (lane == s - 1) sbv = x;
        }
        if (lane < NSUP) sbl[lane] = (unsigned char)sbv;
    }
    __syncthreads();

    // P3: backfill chunk boundaries within each super (readlane chains)
#pragma unroll
    for (int r = 0; r < 2; ++r) {
        int s = wid * 2 + r;
        int rows[SUPC];
#pragma unroll
        for (int q = 1; q < SUPC; ++q)
            rows[q] = maps[(s * SUPC + q) * 64 + lane];
        int x = __builtin_amdgcn_readfirstlane((int)sbl[s]);
        int bv = 0;
        if (lane == SUPC - 1) bv = x;
#pragma unroll
        for (int q = SUPC - 1; q >= 1; --q) {
            x = __builtin_amdgcn_readlane(rows[q], x);
            if (lane == q - 1) bv = x;
        }
        if (lane < SUPC) bnd[s * SUPC + lane] = (unsigned char)bv;
    }
}

// ---------------------------------------------------------------------------
// Phase 4: per-chunk tag fill — readlane chain, coalesced 128 B store (R6).
// ---------------------------------------------------------------------------
__global__ __launch_bounds__(64) void bt_fill(
        const unsigned char* __restrict__ bp, const unsigned char* __restrict__ bnd,
        float* __restrict__ out) {
    const int c = blockIdx.x;
    const int lane = threadIdx.x;
    int rows[LC];
#pragma unroll
    for (int tt = 1; tt < LC; ++tt)
        rows[tt] = bp[((size_t)c * LC + tt) * 64 + lane];
    int x = __builtin_amdgcn_readfirstlane((int)bnd[c]);
    int tv = 0;
    if (lane == LC - 1) tv = x;
#pragma unroll
    for (int tt = LC - 1; tt >= 1; --tt) {
        x = __builtin_amdgcn_readlane(rows[tt], x);
        if (lane == tt - 1) tv = x;
    }
    if (lane < LC) out[1 + c * LC + lane] = (float)tv;
}

extern "C" void kernel_launch(void* const* d_in, const int* in_sizes, int n_in,
                              void* d_out, int out_size, void* d_ws, size_t ws_size,
                              hipStream_t stream) {
    const float* feats = (const float*)d_in[0];   // [S, D]
    const float* W     = (const float*)d_in[1];   // [L, D]
    const float* b     = (const float*)d_in[2];   // [L]
    const float* T     = (const float*)d_in[3];   // [L, L]
    float* out = (float*)d_out;                   // [0]=score, [1..S]=tags

    char* ws = (char*)d_ws;
    float*          em     = (float*)(ws + EM_OFF);
    unsigned char*  bp     = (unsigned char*)(ws + BP_OFF);
    unsigned char*  maps   = (unsigned char*)(ws + MAPS_OFF);
    unsigned char*  bnd    = (unsigned char*)(ws + BND_OFF);
    float*          win    = (float*)(ws + WIN_OFF);
    float*          endsc  = (float*)(ws + END_OFF);
    float*          finrow = (float*)(ws + FIN_OFF);
    unsigned short* Wbf    = (unsigned short*)(ws + WBF_OFF);

    wconv_kernel<<<(L_LAB * D_DIM) / 256, 256, 0, stream>>>(W, Wbf);
    emis_kernel<<<S_LEN / 32, 256, 0, stream>>>(feats, Wbf, b, em);
    fwd_chunks<<<NCH, 64, 0, stream>>>(em, T, bp, maps, win, endsc, finrow);
    finish_kernel<<<1, 1024, 0, stream>>>(T, win, endsc, finrow, maps, out, bnd);
    bt_fill<<<NCH, 64, 0, stream>>>(bp, bnd, out);
}

// Round 11
// 248.153 us; speedup vs baseline: 2.3326x; 1.0133x over previous
//
#include <hip/hip_runtime.h>

#define S_LEN 32768
#define D_DIM 1024
#define L_LAB 64
#define LC 32                     // owned steps per chunk (fwd + backtrack unit)
#define NCH (S_LEN / LC)          // 1024 chunks = 1024 waves (fills all SIMDs)
#define H_WARM 12                 // warm-up steps
#define NSUP 32                   // supers in finish
#define SUPC 32                   // chunks per super (NSUP*SUPC == NCH)

// workspace layout (bytes)
#define EM_OFF   0                                  // float em[S][64]   = 8 MB
#define BP_OFF   (S_LEN * 64 * 4)                   // uchar bp[S][64]   = 2 MB
#define MAPS_OFF (BP_OFF + S_LEN * 64)              // uchar maps[NCH][64] = 64 KB
#define BND_OFF  (MAPS_OFF + NCH * 64)              // uchar bnd[NCH]
#define WIN_OFF  (BND_OFF + 1024)                   // float win[NCH]
#define END_OFF  (WIN_OFF + NCH * 4)                // float endsc[NCH]
#define FIN_OFF  (END_OFF + NCH * 4)                // float finrow[64]

typedef __attribute__((ext_vector_type(8))) short short8;
typedef __attribute__((ext_vector_type(4))) float floatx4;

__device__ inline unsigned short f32_bf16_rne(float f) {
    unsigned v = __float_as_uint(f);
    v += 0x7FFFu + ((v >> 16) & 1u);
    return (unsigned short)(v >> 16);
}
__device__ inline unsigned umax(unsigned a, unsigned b) { return a > b ? a : b; }

// ---------------------------------------------------------------------------
// Phase 1 (R10): emissions = bf16(feats) @ bf16(W).T + b.
// wconv DELETED: B staged directly from float W with the same RNE pack
// (W is 256 KB, L2/L3-resident; doubled B-stage bytes ~4 us aggregate,
// overlapped — vs one whole launch + wconv exec saved). em is bit-identical
// to R6/R9 (same f32_bf16_rne on same values, same MFMA shapes/order).
// 64-row tile (R6 shape; measured equal to 32-row, half the W re-reads).
// ---------------------------------------------------------------------------
__global__ __launch_bounds__(256) __attribute__((amdgpu_waves_per_eu(2, 2)))
void emis_kernel(
        const float* __restrict__ feats, const float* __restrict__ W,
        const float* __restrict__ bvec, float* __restrict__ em) {
    __shared__ __align__(16) unsigned short As[64 * 72];   // bf16 feats tile
    __shared__ __align__(16) unsigned short Bs[64 * 72];   // bf16 W tile

    const int tid = threadIdx.x;
    const int lan = tid & 15;
    const int q   = (tid >> 4) & 3;
    const int w   = tid >> 6;
    const int row0 = blockIdx.x * 64;

    floatx4 acc[4];
#pragma unroll
    for (int nt = 0; nt < 4; ++nt) acc[nt] = (floatx4){0.f, 0.f, 0.f, 0.f};

    for (int kb = 0; kb < D_DIM; kb += 64) {
        __syncthreads();
        // stage A: 64 rows x 64 k; 1024 granules of 4 el, 4/thread
#pragma unroll
        for (int i = 0; i < 4; ++i) {
            int gi = tid + i * 256;
            int m = gi >> 4, g = gi & 15;
            float4 v = *(const float4*)&feats[(size_t)(row0 + m) * D_DIM + kb + g * 4];
            unsigned h0 = f32_bf16_rne(v.x) | ((unsigned)f32_bf16_rne(v.y) << 16);
            unsigned h1 = f32_bf16_rne(v.z) | ((unsigned)f32_bf16_rne(v.w) << 16);
            *(uint2*)&As[m * 72 + g * 4] = (uint2){h0, h1};
        }
        // stage B: 64 labels x 64 k from float W, RNE pack (512 uint4, 2/thr)
#pragma unroll
        for (int i = 0; i < 2; ++i) {
            int gi = tid + i * 256;
            int m = gi >> 3, g = gi & 7;
            const float* wr = &W[(size_t)m * D_DIM + kb + g * 8];
            float4 w0 = *(const float4*)&wr[0];
            float4 w1 = *(const float4*)&wr[4];
            unsigned u0 = f32_bf16_rne(w0.x) | ((unsigned)f32_bf16_rne(w0.y) << 16);
            unsigned u1 = f32_bf16_rne(w0.z) | ((unsigned)f32_bf16_rne(w0.w) << 16);
            unsigned u2 = f32_bf16_rne(w1.x) | ((unsigned)f32_bf16_rne(w1.y) << 16);
            unsigned u3 = f32_bf16_rne(w1.z) | ((unsigned)f32_bf16_rne(w1.w) << 16);
            *(uint4*)&Bs[m * 72 + g * 8] = (uint4){u0, u1, u2, u3};
        }
        __syncthreads();

#pragma unroll
        for (int cc = 0; cc < 2; ++cc) {
            int koff = cc * 32 + q * 8;
            int m_loc = w * 16 + lan;
            short8 av = *(const short8*)&As[m_loc * 72 + koff];
#pragma unroll
            for (int nt = 0; nt < 4; ++nt) {
                int label = nt * 16 + lan;
                short8 bv = *(const short8*)&Bs[label * 72 + koff];
                acc[nt] = __builtin_amdgcn_mfma_f32_16x16x32_bf16(av, bv, acc[nt], 0, 0, 0);
            }
        }
    }

    // epilogue: C/D layout col=lane&15, row=(lane>>4)*4+reg
#pragma unroll
    for (int nt = 0; nt < 4; ++nt) {
        int label = nt * 16 + lan;
        float bias = bvec[label];
#pragma unroll
        for (int r = 0; r < 4; ++r) {
            int row = row0 + w * 16 + q * 4 + r;
            em[(size_t)row * 64 + label] = acc[nt][r] + bias;
        }
    }
}

// ---------------------------------------------------------------------------
// Phase 2: forward + inline argmax + inline map composition (unchanged).
// EXACT shifted key (proven absmax 60): candidates v = sc_i + Trow_b[i] in
// [12.6k, 33k] subset [2^13, 2^17) => top 6 bits of asint(v) constant.
// key = (asint(v) << 6) | (63-i) compared unsigned; value reconstructed
// exactly via (key >> 6) | 0x44000000.
// ---------------------------------------------------------------------------
__global__ __launch_bounds__(64) __attribute__((amdgpu_waves_per_eu(1, 1)))
void fwd_chunks(
        const float* __restrict__ em, const float* __restrict__ T,
        unsigned char* __restrict__ bp, unsigned char* __restrict__ maps,
        float* __restrict__ win, float* __restrict__ endsc,
        float* __restrict__ finrow) {
    const int j = threadIdx.x;
    const int c = blockIdx.x;
    const int a = c * LC;
    const int bend = a + LC;

    float Trow[64];
#pragma unroll
    for (int i = 0; i < 16; ++i)
        ((float4*)Trow)[i] = ((const float4*)(T + j * 64))[i];
#pragma unroll
    for (int i = 0; i < 64; ++i) Trow[i] += 32768.0f;

    int t0 = a - 1 - H_WARM;
    if (t0 < 0) t0 = 0;

    float sc;
    if (t0 == 0) {
        sc = Trow[0] + (em[j] - 32768.0f);
    } else {
        sc = em[(size_t)t0 * 64 + j];
    }

    // value-only step (warm-up); 4 accumulators, 8-deep max3 chains.
    auto step = [&](float e) {
        int sci = __float_as_int(sc);
        float v0 = 0.f, v1 = 0.f, v2 = 0.f, v3 = 0.f;   // candidates all > 12000
#pragma unroll
        for (int k = 0; k < 8; ++k) {
            float a0 = __int_as_float(__builtin_amdgcn_readlane(sci, k)) + Trow[k];
            float a1 = __int_as_float(__builtin_amdgcn_readlane(sci, k + 16)) + Trow[k + 16];
            float a2 = __int_as_float(__builtin_amdgcn_readlane(sci, k + 32)) + Trow[k + 32];
            float a3 = __int_as_float(__builtin_amdgcn_readlane(sci, k + 48)) + Trow[k + 48];
            v0 = fmaxf(fmaxf(v0, a0), a1);   // v_max3_f32
            v1 = fmaxf(fmaxf(v1, a2), a3);
        }
#pragma unroll
        for (int k = 8; k < 16; ++k) {
            float a0 = __int_as_float(__builtin_amdgcn_readlane(sci, k)) + Trow[k];
            float a1 = __int_as_float(__builtin_amdgcn_readlane(sci, k + 16)) + Trow[k + 16];
            float a2 = __int_as_float(__builtin_amdgcn_readlane(sci, k + 32)) + Trow[k + 32];
            float a3 = __int_as_float(__builtin_amdgcn_readlane(sci, k + 48)) + Trow[k + 48];
            v2 = fmaxf(fmaxf(v2, a0), a1);
            v3 = fmaxf(fmaxf(v3, a2), a3);
        }
        sc = e + fmaxf(fmaxf(v0, v1), fmaxf(v2, v3));
    };

    int bi = 0;
    // key-only step (owned): exact value + argmax from the shifted key.
    auto stepx = [&](float e) {
        int sci = __float_as_int(sc);
        unsigned m0 = 0u, m1 = 0u, m2 = 0u, m3 = 0u;
#pragma unroll
        for (int k = 0; k < 8; ++k) {
            float a0 = __int_as_float(__builtin_amdgcn_readlane(sci, k)) + Trow[k];
            float a1 = __int_as_float(__builtin_amdgcn_readlane(sci, k + 16)) + Trow[k + 16];
            float a2 = __int_as_float(__builtin_amdgcn_readlane(sci, k + 32)) + Trow[k + 32];
            float a3 = __int_as_float(__builtin_amdgcn_readlane(sci, k + 48)) + Trow[k + 48];
            unsigned k0 = ((unsigned)__float_as_int(a0) << 6) | (unsigned)(63 - k);
            unsigned k1 = ((unsigned)__float_as_int(a1) << 6) | (unsigned)(63 - (k + 16));
            unsigned k2 = ((unsigned)__float_as_int(a2) << 6) | (unsigned)(63 - (k + 32));
            unsigned k3 = ((unsigned)__float_as_int(a3) << 6) | (unsigned)(63 - (k + 48));
            m0 = umax(umax(m0, k0), k1);     // v_max3_u32
            m1 = umax(umax(m1, k2), k3);
        }
#pragma unroll
        for (int k = 8; k < 16; ++k) {
            float a0 = __int_as_float(__builtin_amdgcn_readlane(sci, k)) + Trow[k];
            float a1 = __int_as_float(__builtin_amdgcn_readlane(sci, k + 16)) + Trow[k + 16];
            float a2 = __int_as_float(__builtin_amdgcn_readlane(sci, k + 32)) + Trow[k + 32];
            float a3 = __int_as_float(__builtin_amdgcn_readlane(sci, k + 48)) + Trow[k + 48];
            unsigned k0 = ((unsigned)__float_as_int(a0) << 6) | (unsigned)(63 - k);
            unsigned k1 = ((unsigned)__float_as_int(a1) << 6) | (unsigned)(63 - (k + 16));
            unsigned k2 = ((unsigned)__float_as_int(a2) << 6) | (unsigned)(63 - (k + 32));
            unsigned k3 = ((unsigned)__float_as_int(a3) << 6) | (unsigned)(63 - (k + 48));
            m2 = umax(umax(m2, k0), k1);
            m3 = umax(umax(m3, k2), k3);
        }
        unsigned mm = umax(umax(m0, m1), umax(m2, m3));
        bi = (int)(mm & 63u) ^ 63;
        sc = e + __uint_as_float((mm >> 6) | 0x44000000u);   // exact
    };

    // ---- warm-up: t in [t0+1, a), no stores ----
    int t = t0 + 1;
    if (t < a) {
        float p0 = em[(size_t)(t + 0) * 64 + j] - 32768.0f;
        float p1 = em[(size_t)(t + 1) * 64 + j] - 32768.0f;
        float p2 = em[(size_t)(t + 2) * 64 + j] - 32768.0f;
        float p3 = em[(size_t)(t + 3) * 64 + j] - 32768.0f;
        for (; t + 3 < a; t += 4) {
            float n0 = em[(size_t)(t + 4) * 64 + j] - 32768.0f;
            float n1 = em[(size_t)(t + 5) * 64 + j] - 32768.0f;
            float n2 = em[(size_t)(t + 6) * 64 + j] - 32768.0f;
            float n3 = em[(size_t)(t + 7) * 64 + j] - 32768.0f;
            step(p0); step(p1); step(p2); step(p3);
            p0 = n0; p1 = n1; p2 = n2; p3 = n3;
        }
        for (; t < a; ++t) { step(p0); p0 = p1; p1 = p2; p2 = p3; }
    }
    if (c > 0 && j == 0) win[c] = sc;   // state-0 score entering owned (t = a-1)

    // ---- owned: argmax + bp store + bpermute map composition ----
    int fmap = j;                        // identity; composes to end->(a-1)
    t = (a > 0) ? a : 1;
    {
        float p0 = em[(size_t)(t + 0) * 64 + j] - 32768.0f;
        float p1 = em[(size_t)(t + 1) * 64 + j] - 32768.0f;
        float p2 = em[(size_t)(t + 2) * 64 + j] - 32768.0f;
        float p3 = em[(size_t)(t + 3) * 64 + j] - 32768.0f;
        for (; t + 3 < bend; t += 4) {
            int t4 = t + 4 > S_LEN - 1 ? S_LEN - 1 : t + 4;
            int t5 = t + 5 > S_LEN - 1 ? S_LEN - 1 : t + 5;
            int t6 = t + 6 > S_LEN - 1 ? S_LEN - 1 : t + 6;
            int t7 = t + 7 > S_LEN - 1 ? S_LEN - 1 : t + 7;
            float n0 = em[(size_t)t4 * 64 + j] - 32768.0f;
            float n1 = em[(size_t)t5 * 64 + j] - 32768.0f;
            float n2 = em[(size_t)t6 * 64 + j] - 32768.0f;
            float n3 = em[(size_t)t7 * 64 + j] - 32768.0f;
            stepx(p0); bp[(size_t)(t + 0) * 64 + j] = (unsigned char)bi;
            fmap = __builtin_amdgcn_ds_bpermute(bi << 2, fmap);
            stepx(p1); bp[(size_t)(t + 1) * 64 + j] = (unsigned char)bi;
            fmap = __builtin_amdgcn_ds_bpermute(bi << 2, fmap);
            stepx(p2); bp[(size_t)(t + 2) * 64 + j] = (unsigned char)bi;
            fmap = __builtin_amdgcn_ds_bpermute(bi << 2, fmap);
            stepx(p3); bp[(size_t)(t + 3) * 64 + j] = (unsigned char)bi;
            fmap = __builtin_amdgcn_ds_bpermute(bi << 2, fmap);
            p0 = n0; p1 = n1; p2 = n2; p3 = n3;
        }
        for (; t < bend; ++t) {
            stepx(p0); bp[(size_t)t * 64 + j] = (unsigned char)bi;
            fmap = __builtin_amdgcn_ds_bpermute(bi << 2, fmap);
            p0 = p1; p1 = p2; p2 = p3;
        }
    }

    maps[c * 64 + j] = (unsigned char)fmap;     // end-of-chunk -> t=a-1
    if (j == 0) endsc[c] = sc;                  // state-0 score at t=bend-1
    if (c == NCH - 1) finrow[j] = sc;           // full final row
}

// ---------------------------------------------------------------------------
// Phase 3: telescoped score + argmax + hierarchical map stitching (unchanged).
// ---------------------------------------------------------------------------
__global__ __launch_bounds__(1024) void finish_kernel(
        const float* __restrict__ T, const float* __restrict__ win,
        const float* __restrict__ endsc, const float* __restrict__ finrow,
        const unsigned char* __restrict__ maps, float* __restrict__ out,
        unsigned char* __restrict__ bnd) {
    __shared__ unsigned char sm[NSUP * 64];
    __shared__ unsigned char sbl[NSUP];
    __shared__ float psum[16];
    const int tid = threadIdx.x;
    const int lane = tid & 63;
    const int wid = tid >> 6;

    // P0: telescoping partial sums (c = tid in [1, NCH))
    float p = 0.f;
    if (tid >= 1 && tid < NCH) p = endsc[tid - 1] - win[tid];
#pragma unroll
    for (int off = 32; off; off >>= 1) p += __shfl_xor(p, off, 64);
    if (lane == 0) psum[wid] = p;

    // P1: supermaps — wave w composes supers 2w, 2w+1 (32 bpermutes each)
#pragma unroll
    for (int r = 0; r < 2; ++r) {
        int s = wid * 2 + r;
        int x = lane;
#pragma unroll 4
        for (int q = SUPC - 1; q >= 0; --q) {
            int mq = maps[(s * SUPC + q) * 64 + lane];
            x = __builtin_amdgcn_ds_bpermute(x << 2, mq);
        }
        sm[s * 64 + lane] = (unsigned char)x;
    }
    __syncthreads();

    // P2: wave 0 — part total, final argmax, serial super chain (readlane)
    if (tid < 64) {
        float part = 0.f;
#pragma unroll
        for (int i = 0; i < 16; ++i) part += psum[i];

        float f = finrow[lane] + T[63 * 64 + lane];
        float best = 0.f; int bt_ = 0;
#pragma unroll
        for (int k = 0; k < 64; ++k) {
            float fv = __int_as_float(__builtin_amdgcn_readlane(__float_as_int(f), k));
            if (k == 0) best = fv;
            else if (fv > best) { best = fv; bt_ = k; }
        }
        if (lane == 0) out[0] = best + part;

        int rows[NSUP];
#pragma unroll
        for (int s = 0; s < NSUP; ++s) rows[s] = sm[s * 64 + lane];
        int x = bt_;                      // uniform across wave 0
        int sbv = 0;
        if (lane == NSUP - 1) sbv = x;
#pragma unroll
        for (int s = NSUP - 1; s >= 1; --s) {
            x = __builtin_amdgcn_readlane(rows[s], x);
            if (lane == s - 1) sbv = x;
        }
        if (lane < NSUP) sbl[lane] = (unsigned char)sbv;
    }
    __syncthreads();

    // P3: backfill chunk boundaries within each super (readlane chains)
#pragma unroll
    for (int r = 0; r < 2; ++r) {
        int s = wid * 2 + r;
        int rows[SUPC];
#pragma unroll
        for (int q = 1; q < SUPC; ++q)
            rows[q] = maps[(s * SUPC + q) * 64 + lane];
        int x = __builtin_amdgcn_readfirstlane((int)sbl[s]);
        int bv = 0;
        if (lane == SUPC - 1) bv = x;
#pragma unroll
        for (int q = SUPC - 1; q >= 1; --q) {
            x = __builtin_amdgcn_readlane(rows[q], x);
            if (lane == q - 1) bv = x;
        }
        if (lane < SUPC) bnd[s * SUPC + lane] = (unsigned char)bv;
    }
}

// ---------------------------------------------------------------------------
// Phase 4: per-chunk tag fill — readlane chain, coalesced 128 B store.
// ---------------------------------------------------------------------------
__global__ __launch_bounds__(64) void bt_fill(
        const unsigned char* __restrict__ bp, const unsigned char* __restrict__ bnd,
        float* __restrict__ out) {
    const int c = blockIdx.x;
    const int lane = threadIdx.x;
    int rows[LC];
#pragma unroll
    for (int tt = 1; tt < LC; ++tt)
        rows[tt] = bp[((size_t)c * LC + tt) * 64 + lane];
    int x = __builtin_amdgcn_readfirstlane((int)bnd[c]);
    int tv = 0;
    if (lane == LC - 1) tv = x;
#pragma unroll
    for (int tt = LC - 1; tt >= 1; --tt) {
        x = __builtin_amdgcn_readlane(rows[tt], x);
        if (lane == tt - 1) tv = x;
    }
    if (lane < LC) out[1 + c * LC + lane] = (float)tv;
}

extern "C" void kernel_launch(void* const* d_in, const int* in_sizes, int n_in,
                              void* d_out, int out_size, void* d_ws, size_t ws_size,
                              hipStream_t stream) {
    const float* feats = (const float*)d_in[0];   // [S, D]
    const float* W     = (const float*)d_in[1];   // [L, D]
    const float* b     = (const float*)d_in[2];   // [L]
    const float* T     = (const float*)d_in[3];   // [L, L]
    float* out = (float*)d_out;                   // [0]=score, [1..S]=tags

    char* ws = (char*)d_ws;
    float*          em     = (float*)(ws + EM_OFF);
    unsigned char*  bp     = (unsigned char*)(ws + BP_OFF);
    unsigned char*  maps   = (unsigned char*)(ws + MAPS_OFF);
    unsigned char*  bnd    = (unsigned char*)(ws + BND_OFF);
    float*          win    = (float*)(ws + WIN_OFF);
    float*          endsc  = (float*)(ws + END_OFF);
    float*          finrow = (float*)(ws + FIN_OFF);

    emis_kernel<<<S_LEN / 64, 256, 0, stream>>>(feats, W, b, em);
    fwd_chunks<<<NCH, 64, 0, stream>>>(em, T, bp, maps, win, endsc, finrow);
    finish_kernel<<<1, 1024, 0, stream>>>(T, win, endsc, finrow, maps, out, bnd);
    bt_fill<<<NCH, 64, 0, stream>>>(bp, bnd, out);
}